// Round 1
// 805.028 us; speedup vs baseline: 1.1281x; 1.1281x over previous
//
#include <hip/hip_runtime.h>
#include <hip/hip_bf16.h>

typedef __bf16 v8bf __attribute__((ext_vector_type(8)));
typedef float  v4f  __attribute__((ext_vector_type(4)));
typedef unsigned short u16;
typedef unsigned int   u32;

#define GAS __attribute__((address_space(1)))
#define LAS __attribute__((address_space(3)))

// constants for this problem
constexpr int C_ = 512;
constexpr int S_ = 3136;        // 56*56
constexpr int B_ = 32;
constexpr int M_ = B_ * S_;     // 100352
constexpr float INV_M = 1.0f / (float)M_;

__device__ __forceinline__ void async16(const u16* g, u16* l) {
  __builtin_amdgcn_global_load_lds((const GAS u32*)g, (LAS u32*)l, 16, 0, 0);
}

__device__ __forceinline__ u16 f2bf(float f) {   // RTNE fp32 -> bf16
  u32 u = __builtin_bit_cast(u32, f);
  u += 0x7fffu + ((u >> 16) & 1u);
  return (u16)(u >> 16);
}
__device__ __forceinline__ float bf2f(u16 h) {
  u32 u = ((u32)h) << 16;
  return __builtin_bit_cast(float, u);
}

// ---------------------------------------------------------------------------
// K1: read X (B,C,S) fp32; write xbf (C, M) bf16 and xbfT (M, C) bf16;
//     accumulate per-channel sums. 64x64 (c,s) tile per block, one b per z.
// ---------------------------------------------------------------------------
__global__ __launch_bounds__(256) void prep_kernel(const float* __restrict__ X,
        u16* __restrict__ xbf, u16* __restrict__ xbfT, float* __restrict__ chsum) {
  __shared__ u16 Ts[64 * 65];            // odd stride: conflict-light transpose
  const int tid = threadIdx.x;
  const int s0 = blockIdx.x * 64;
  const int c0 = blockIdx.y * 64;
  const int b  = blockIdx.z;

  // phase 1: coalesced read, write xbf, stage LDS tile, channel partial sums
  const int i  = tid >> 2;               // channel row 0..63
  const int jc = (tid & 3) * 16;         // s offset
  const float* xp = X + (b * C_ + c0 + i) * S_ + s0 + jc;
  u16* op = xbf + (c0 + i) * M_ + b * S_ + s0 + jc;
  float ssum = 0.f;
  #pragma unroll
  for (int u = 0; u < 4; ++u) {
    float4 xv = *(const float4*)(xp + u * 4);
    ssum += xv.x + xv.y + xv.z + xv.w;
    u16 e0 = f2bf(xv.x), e1 = f2bf(xv.y), e2 = f2bf(xv.z), e3 = f2bf(xv.w);
    *(ushort4*)(op + u * 4) = make_ushort4(e0, e1, e2, e3);
    const int lb = i * 65 + jc + u * 4;
    Ts[lb + 0] = e0; Ts[lb + 1] = e1; Ts[lb + 2] = e2; Ts[lb + 3] = e3;
  }
  ssum += __shfl_down(ssum, 2, 4);
  ssum += __shfl_down(ssum, 1, 4);
  if ((tid & 3) == 0) atomicAdd(&chsum[c0 + i], ssum);
  __syncthreads();

  // phase 2: transposed write; each 8-lane group writes one 128B row segment
  const int lane = tid & 63, wv = tid >> 6;
  #pragma unroll
  for (int p = 0; p < 2; ++p) {
    const int j  = p * 32 + wv * 8 + (lane >> 3);   // s-row 0..63
    const int cc = (lane & 7) * 8;                  // c offset 0..56
    u16 tmp[8];
    #pragma unroll
    for (int e = 0; e < 8; ++e) tmp[e] = Ts[(cc + e) * 65 + j];
    u16* tp = xbfT + (b * S_ + s0 + j) * C_ + c0 + cc;
    *(ushort4*)(tp + 0) = make_ushort4(tmp[0], tmp[1], tmp[2], tmp[3]);
    *(ushort4*)(tp + 4) = make_ushort4(tmp[4], tmp[5], tmp[6], tmp[7]);
  }
}

// ---------------------------------------------------------------------------
// K3: Sigma partials, SYMMETRIC: only upper-triangle tile pairs (10 of 16).
// part[z][t][128][128] = sum_{k in slice z} x[ti-rows,k] x[tj-rows,k]
// 1D grid 320: z = bid&31 so all 10 blocks of a slice land on XCD z%8
// (slice = 3.2 MB, L2-fits; round-robin dispatch maps bid%8 -> XCD).
// ---------------------------------------------------------------------------
__global__ __launch_bounds__(256, 2) void sigma_gemm(const u16* __restrict__ xbf,
                                                     float* __restrict__ part) {
  __shared__ u16 As[128 * 64];
  __shared__ u16 Bs[128 * 64];
  const int tid = threadIdx.x;
  const int bid = blockIdx.x;
  const int z = bid & 31;
  const int t = bid >> 5;                       // 0..9 triangle tile index
  const int ti = (t >= 9) ? 3 : (t >= 7) ? 2 : (t >= 4) ? 1 : 0;
  const int tb = (t >= 9) ? 9 : (t >= 7) ? 7 : (t >= 4) ? 4 : 0;
  const int tj = ti + (t - tb);
  const int kbase = z * S_;
  const int srow = tid >> 3;
  const int scol = (tid & 7) * 8;
  const int lane = tid & 63, wv = tid >> 6;
  const int wm = (wv & 1) * 64, wn = (wv >> 1) * 64;
  const int lr = lane & 15, lq = lane >> 4;
  const u16* gA = xbf + (ti * 128) * M_ + kbase + scol;
  const u16* gB = xbf + (tj * 128) * M_ + kbase + scol;
  v4f acc[4][4] = {};
  for (int it = 0; it < 49; ++it) {
    const int k0 = it * 64;
    #pragma unroll
    for (int q = 0; q < 4; ++q) {
      const int r = q * 32 + srow;
      async16(gA + r * M_ + k0, &As[r * 64 + scol]);
      async16(gB + r * M_ + k0, &Bs[r * 64 + scol]);
    }
    __syncthreads();
    #pragma unroll
    for (int kk = 0; kk < 2; ++kk) {
      v8bf a[4], b[4];
      #pragma unroll
      for (int x = 0; x < 4; ++x) a[x] = *(const v8bf*)&As[(wm + x*16 + lr)*64 + kk*32 + lq*8];
      #pragma unroll
      for (int x = 0; x < 4; ++x) b[x] = *(const v8bf*)&Bs[(wn + x*16 + lr)*64 + kk*32 + lq*8];
      #pragma unroll
      for (int mi = 0; mi < 4; ++mi)
        #pragma unroll
        for (int ni = 0; ni < 4; ++ni)
          acc[mi][ni] = __builtin_amdgcn_mfma_f32_16x16x32_bf16(a[mi], b[ni], acc[mi][ni], 0, 0, 0);
    }
    __syncthreads();
  }
  float* op = part + (size_t)(z * 10 + t) * (128 * 128);
  #pragma unroll
  for (int mi = 0; mi < 4; ++mi) {
    const int li = wm + mi * 16 + lq * 4;
    #pragma unroll
    for (int ni = 0; ni < 4; ++ni) {
      const int lj = wn + ni * 16 + lr;
      #pragma unroll
      for (int r = 0; r < 4; ++r)
        op[(li + r) * 128 + lj] = acc[mi][ni][r];
    }
  }
}

// ---------------------------------------------------------------------------
// K4: Sigma = sum_z part/m - mu mu^T + EPS I, mirrored to lower triangle;
//     accumulate trace atomically. Grid covers the 10 triangle tiles.
// ---------------------------------------------------------------------------
__global__ __launch_bounds__(256) void reduce_sigma(const float* __restrict__ part,
        const float* __restrict__ chsum, float* __restrict__ Sigma,
        float* __restrict__ trace) {
  const int idx = blockIdx.x * 256 + threadIdx.x;   // 0 .. 10*16384-1
  const int t = idx >> 14;
  const int r = idx & 16383;
  const int ii = r >> 7, jj = r & 127;
  const int ti = (t >= 9) ? 3 : (t >= 7) ? 2 : (t >= 4) ? 1 : 0;
  const int tb = (t >= 9) ? 9 : (t >= 7) ? 7 : (t >= 4) ? 4 : 0;
  const int tj = ti + (t - tb);
  const int i = ti * 128 + ii, j = tj * 128 + jj;
  float s = 0.f;
  #pragma unroll 8
  for (int z = 0; z < 32; ++z) s += part[(size_t)(z * 10 + t) * 16384 + r];
  float val = s * INV_M - (chsum[i] * INV_M) * (chsum[j] * INV_M);
  if (i == j) val += 1e-5f;
  Sigma[i * 512 + j] = val;
  if (i != j) Sigma[j * 512 + i] = val;     // mirror (symmetric)
  if (i == j) atomicAdd(trace, val);
}

// ---------------------------------------------------------------------------
// K5: SN = Sigma/trace -> bf16 hi/lo split; P = I (fp32 + split);
//     rot -> bf16 hi/lo split.
// ---------------------------------------------------------------------------
__global__ __launch_bounds__(256) void init_ns(const float* __restrict__ Sigma,
        const float* __restrict__ trace, const float* __restrict__ rot,
        u16* __restrict__ SNhi, u16* __restrict__ SNlo,
        float* __restrict__ P, u16* __restrict__ Phi, u16* __restrict__ Plo,
        u16* __restrict__ rothi, u16* __restrict__ rotlo) {
  const int idx = blockIdx.x * 256 + threadIdx.x;
  const float rtr = 1.0f / trace[0];
  const float sn = Sigma[idx] * rtr;
  u16 h = f2bf(sn);
  SNhi[idx] = h; SNlo[idx] = f2bf(sn - bf2f(h));
  const bool diag = (idx >> 9) == (idx & 511);
  P[idx] = diag ? 1.0f : 0.f;
  Phi[idx] = diag ? (u16)0x3F80 : (u16)0;   // bf16(1.0)
  Plo[idx] = 0;
  const float rv = rot[idx];
  u16 rh = f2bf(rv);
  rothi[idx] = rh; rotlo[idx] = f2bf(rv - bf2f(rh));
}

// ---------------------------------------------------------------------------
// K6: split-bf16 MFMA 512^3 matmul. A,B given as bf16 (hi,lo) splits;
//     C = Ahi*Bhi + Ahi*Blo + Alo*Bhi  (lo*lo dropped; ~2^-17 rel err).
// 64x64 tile/block, 4 waves each a 32x32 quadrant, BK=64.
// LDS fragment reads XOR-swizzled (G4 fix for 128B-stride row-major tiles);
// swizzle applied on the GLOBAL source column since global_load_lds writes
// linearly (rule #21: both-sides-or-neither).
// mode 0 (grid z=2): Cz = A@Bz -> write hi/lo splits only (T1, T2)
// mode 1: U = A@B0; P = 1.5P - 0.5U (fp32); write split(P) to C0hi/C0lo
// mode 2: W = A@B0; s=sqrt(1/trace); M2f = W*s fp32, M2bf = bf16(W*s)
// Guard: iter >= *Tptr -> no-op (matches reference loop count).
// ---------------------------------------------------------------------------
__global__ __launch_bounds__(256) void ns_mm(
    const u16* __restrict__ Ahi, const u16* __restrict__ Alo,
    const u16* __restrict__ B0hi, const u16* __restrict__ B0lo,
    const u16* __restrict__ B1hi, const u16* __restrict__ B1lo,
    u16* __restrict__ C0hi, u16* __restrict__ C0lo,
    u16* __restrict__ C1hi, u16* __restrict__ C1lo,
    float* __restrict__ P, const float* __restrict__ trace,
    float* __restrict__ M2f, u16* __restrict__ M2bf,
    const int* __restrict__ Tptr, int iter, int mode) {
  if (Tptr && iter >= Tptr[0]) return;
  __shared__ u16 Ah[64 * 64];
  __shared__ u16 Al[64 * 64];
  __shared__ u16 Bh[64 * 64];
  __shared__ u16 Bl[64 * 64];
  const int tid = threadIdx.x;
  const int tj = blockIdx.x, ti = blockIdx.y, zb = blockIdx.z;
  const u16* Bhip = zb ? B1hi : B0hi;
  const u16* Blop = zb ? B1lo : B0lo;
  const int r  = tid >> 3;                 // staging row 0..31
  const int sg = tid & 7;                  // 16B segment
  const int swz = (sg ^ (r & 7)) * 8;      // swizzled source column (u16 units)
  const int lofs = r * 64 + sg * 8;        // linear LDS dest (= tid*16 bytes)
  const u16* gAh = Ahi  + (ti * 64 + r) * 512 + swz;
  const u16* gAl = Alo  + (ti * 64 + r) * 512 + swz;
  const u16* gBh = Bhip + (tj * 64 + r) * 512 + swz;
  const u16* gBl = Blop + (tj * 64 + r) * 512 + swz;
  const int lane = tid & 63, wv = tid >> 6;
  const int wr = wv >> 1, wc = wv & 1;     // wave quadrant (row, col)
  const int lr = lane & 15, lq = lane >> 4;
  v4f acc[2][2] = {};
  for (int it = 0; it < 8; ++it) {
    const int k0 = it * 64;
    async16(gAh + k0,            &Ah[lofs]);
    async16(gAh + k0 + 32 * 512, &Ah[lofs + 32 * 64]);
    async16(gAl + k0,            &Al[lofs]);
    async16(gAl + k0 + 32 * 512, &Al[lofs + 32 * 64]);
    async16(gBh + k0,            &Bh[lofs]);
    async16(gBh + k0 + 32 * 512, &Bh[lofs + 32 * 64]);
    async16(gBl + k0,            &Bl[lofs]);
    async16(gBl + k0 + 32 * 512, &Bl[lofs + 32 * 64]);
    __syncthreads();
    #pragma unroll
    for (int kk = 0; kk < 2; ++kk) {
      v8bf ah[2], al[2], bh[2], bl[2];
      const int col = ((kk * 4 + lq) ^ (lr & 7)) * 8;   // un-swizzle on read
      #pragma unroll
      for (int x = 0; x < 2; ++x) {
        const int rowA = (wr * 32 + x * 16 + lr) * 64;
        ah[x] = *(const v8bf*)&Ah[rowA + col];
        al[x] = *(const v8bf*)&Al[rowA + col];
        const int rowB = (wc * 32 + x * 16 + lr) * 64;
        bh[x] = *(const v8bf*)&Bh[rowB + col];
        bl[x] = *(const v8bf*)&Bl[rowB + col];
      }
      #pragma unroll
      for (int mi = 0; mi < 2; ++mi)
        #pragma unroll
        for (int ni = 0; ni < 2; ++ni) {
          acc[mi][ni] = __builtin_amdgcn_mfma_f32_16x16x32_bf16(ah[mi], bh[ni], acc[mi][ni], 0, 0, 0);
          acc[mi][ni] = __builtin_amdgcn_mfma_f32_16x16x32_bf16(ah[mi], bl[ni], acc[mi][ni], 0, 0, 0);
          acc[mi][ni] = __builtin_amdgcn_mfma_f32_16x16x32_bf16(al[mi], bh[ni], acc[mi][ni], 0, 0, 0);
        }
    }
    __syncthreads();
  }
  u16* Chi = zb ? C1hi : C0hi;
  u16* Clo = zb ? C1lo : C0lo;
  const float sc = (mode == 2) ? sqrtf(1.0f / trace[0]) : 0.f;
  #pragma unroll
  for (int mi = 0; mi < 2; ++mi) {
    const int gr0 = ti * 64 + wr * 32 + mi * 16 + lq * 4;
    #pragma unroll
    for (int ni = 0; ni < 2; ++ni) {
      const int gc = tj * 64 + wc * 32 + ni * 16 + lr;
      #pragma unroll
      for (int q = 0; q < 4; ++q) {
        const int o = (gr0 + q) * 512 + gc;
        const float vv = acc[mi][ni][q];
        if (mode == 0) {
          u16 h = f2bf(vv);
          Chi[o] = h; Clo[o] = f2bf(vv - bf2f(h));
        } else if (mode == 1) {
          const float nv = 1.5f * P[o] - 0.5f * vv;
          P[o] = nv;
          u16 h = f2bf(nv);
          Chi[o] = h; Clo[o] = f2bf(nv - bf2f(h));
        } else {
          const float w = vv * sc;
          M2f[o] = w; M2bf[o] = f2bf(w);
        }
      }
    }
  }
}

// ---------------------------------------------------------------------------
// K8: v[d] = sum_c M2[d,c] * mean[c]
// ---------------------------------------------------------------------------
__global__ __launch_bounds__(256) void calc_v(const float* __restrict__ M2f,
        const float* __restrict__ chsum, float* __restrict__ v) {
  const int d = blockIdx.x * 256 + threadIdx.x;
  float s = 0.f;
  for (int c = 0; c < 512; ++c) s += M2f[d * 512 + c] * (chsum[c] * INV_M);
  v[d] = s;
}

// ---------------------------------------------------------------------------
// K9: out[b,d,s] = sum_c M2bf[d,c] * xbfT[b*S+s, c] - v[d]
// NT GEMM: M=512 (d, 4 tiles), N=100352 (m, 784 tiles), K=512 (8 BK iters)
// ---------------------------------------------------------------------------
__global__ __launch_bounds__(256, 2) void out_gemm(const u16* __restrict__ Abf,
        const u16* __restrict__ Bt, const float* __restrict__ v, float* __restrict__ out) {
  __shared__ u16 As[128 * 64];
  __shared__ u16 Bs[128 * 64];
  const int tid = threadIdx.x;
  const int tn = blockIdx.x, td = blockIdx.y;
  const int srow = tid >> 3, scol = (tid & 7) * 8;
  const int lane = tid & 63, wv = tid >> 6;
  const int wm = (wv & 1) * 64, wn = (wv >> 1) * 64;
  const int lr = lane & 15, lq = lane >> 4;
  const u16* gA = Abf + (td * 128) * 512 + scol;
  const u16* gB = Bt + (tn * 128) * 512 + scol;
  v4f acc[4][4] = {};
  for (int it = 0; it < 8; ++it) {
    const int k0 = it * 64;
    #pragma unroll
    for (int q = 0; q < 4; ++q) {
      const int r = q * 32 + srow;
      async16(gA + r * 512 + k0, &As[r * 64 + scol]);
      async16(gB + r * 512 + k0, &Bs[r * 64 + scol]);
    }
    __syncthreads();
    #pragma unroll
    for (int kk = 0; kk < 2; ++kk) {
      v8bf a[4], b[4];
      #pragma unroll
      for (int x = 0; x < 4; ++x) a[x] = *(const v8bf*)&As[(wm + x*16 + lr)*64 + kk*32 + lq*8];
      #pragma unroll
      for (int x = 0; x < 4; ++x) b[x] = *(const v8bf*)&Bs[(wn + x*16 + lr)*64 + kk*32 + lq*8];
      #pragma unroll
      for (int mi = 0; mi < 4; ++mi)
        #pragma unroll
        for (int ni = 0; ni < 4; ++ni)
          acc[mi][ni] = __builtin_amdgcn_mfma_f32_16x16x32_bf16(a[mi], b[ni], acc[mi][ni], 0, 0, 0);
    }
    __syncthreads();
  }
  #pragma unroll
  for (int mi = 0; mi < 4; ++mi) {
    const int d0 = td * 128 + wm + mi * 16 + lq * 4;
    const float vd0 = v[d0 + 0], vd1 = v[d0 + 1], vd2 = v[d0 + 2], vd3 = v[d0 + 3];
    #pragma unroll
    for (int ni = 0; ni < 4; ++ni) {
      const unsigned mcol = tn * 128 + wn + ni * 16 + lr;
      const unsigned bb = mcol / 3136u;          // magic-mul div (const)
      const unsigned ss = mcol - bb * 3136u;
      const int obase = (int)(bb * 512u) * 3136 + (int)ss;
      out[obase + (d0 + 0) * 3136] = acc[mi][ni][0] - vd0;
      out[obase + (d0 + 1) * 3136] = acc[mi][ni][1] - vd1;
      out[obase + (d0 + 2) * 3136] = acc[mi][ni][2] - vd2;
      out[obase + (d0 + 3) * 3136] = acc[mi][ni][3] - vd3;
    }
  }
}

// ---------------------------------------------------------------------------
extern "C" void kernel_launch(void* const* d_in, const int* in_sizes, int n_in,
                              void* d_out, int out_size, void* d_ws, size_t ws_size,
                              hipStream_t stream) {
  const float* X   = (const float*)d_in[0];
  const float* rot = (const float*)d_in[1];
  const int*   T   = (const int*)d_in[2];
  float* out = (float*)d_out;

  char* ws = (char*)d_ws;
  size_t off = 0;
  auto alloc = [&](size_t bytes) -> char* {
    char* p = ws + off;
    off += (bytes + 255) & ~(size_t)255;
    return p;
  };
  u16*   xbf   = (u16*)alloc((size_t)C_ * M_ * 2);     // 102.8 MB
  u16*   xbfT  = (u16*)alloc((size_t)M_ * C_ * 2);     // 102.8 MB
  float* part  = (float*)alloc((size_t)320 * 16384 * 4); // 21 MB (triangle tiles)
  float* Sigma = (float*)alloc((size_t)C_ * C_ * 4);
  float* P     = (float*)alloc((size_t)C_ * C_ * 4);
  float* M2f   = (float*)alloc((size_t)C_ * C_ * 4);
  u16*   SNhi  = (u16*)alloc((size_t)C_ * C_ * 2);
  u16*   SNlo  = (u16*)alloc((size_t)C_ * C_ * 2);
  u16*   Phi   = (u16*)alloc((size_t)C_ * C_ * 2);
  u16*   Plo   = (u16*)alloc((size_t)C_ * C_ * 2);
  u16*   T1hi  = (u16*)alloc((size_t)C_ * C_ * 2);
  u16*   T1lo  = (u16*)alloc((size_t)C_ * C_ * 2);
  u16*   T2hi  = (u16*)alloc((size_t)C_ * C_ * 2);
  u16*   T2lo  = (u16*)alloc((size_t)C_ * C_ * 2);
  u16*   rothi = (u16*)alloc((size_t)C_ * C_ * 2);
  u16*   rotlo = (u16*)alloc((size_t)C_ * C_ * 2);
  u16*   M2bf  = (u16*)alloc((size_t)C_ * C_ * 2);
  float* chsum = (float*)alloc(2048);
  float* trace = (float*)alloc(256);
  float* v     = (float*)alloc(2048);
  (void)ws_size; (void)in_sizes; (void)n_in; (void)out_size;

  // zero the atomic accumulators (chsum + trace are contiguous)
  hipMemsetAsync(chsum, 0, 2048 + 256, stream);

  prep_kernel<<<dim3(49, 8, 32), 256, 0, stream>>>(X, xbf, xbfT, chsum);
  sigma_gemm<<<dim3(320), 256, 0, stream>>>(xbf, part);
  reduce_sigma<<<dim3(640), 256, 0, stream>>>(part, chsum, Sigma, trace);
  init_ns<<<dim3(1024), 256, 0, stream>>>(Sigma, trace, rot, SNhi, SNlo, P, Phi, Plo, rothi, rotlo);

  for (int iter = 0; iter < 10; ++iter) {
    // z=0: T1 = P@P ; z=1: T2 = P@SN   (split-bf16 MFMA, writes hi/lo splits)
    ns_mm<<<dim3(8, 8, 2), 256, 0, stream>>>(Phi, Plo, Phi, Plo, SNhi, SNlo,
        T1hi, T1lo, T2hi, T2lo, P, trace, M2f, M2bf, T, iter, 0);
    // P = 1.5P - 0.5 * T1@T2 (= 1.5P - 0.5 P^3 SN); refresh split(P)
    ns_mm<<<dim3(8, 8, 1), 256, 0, stream>>>(T1hi, T1lo, T2hi, T2lo, nullptr, nullptr,
        Phi, Plo, nullptr, nullptr, P, trace, M2f, M2bf, T, iter, 1);
  }
  // M2 = rot @ P * sqrt(1/trace)  (fp32 + bf16 copies)
  ns_mm<<<dim3(8, 8, 1), 256, 0, stream>>>(rothi, rotlo, Phi, Plo, nullptr, nullptr,
      Phi, Plo, nullptr, nullptr, P, trace, M2f, M2bf, nullptr, 0, 2);
  calc_v<<<dim3(2), 256, 0, stream>>>(M2f, chsum, v);
  out_gemm<<<dim3(784, 4), 256, 0, stream>>>(M2bf, xbfT, v, out);
}